// Round 1
// baseline (3527.187 us; speedup 1.0000x reference)
//
#include <hip/hip_runtime.h>
#include <math.h>

// Problem constants (reference: B=2, L=2048, E=1024, H=16, D=64)
#define BB 2
#define LL 2048
#define EE 1024
#define HH 16
#define DD 64

// ---------------------------------------------------------------------------
// GEMM (NT): C[M][N] = A[M][K] * W[N][K]^T
// A row-major [M][K], W row-major [N][K] (k innermost in both -> coalesced
// float4 loads along k). LDS tiles stored k-major ([kk][row]) so the compute
// loop reads contiguous float4 fragments with ds_read_b128.
// Tile 64x64, BK=32, 256 threads, 4x4 accumulator per thread.
// ---------------------------------------------------------------------------
__global__ __launch_bounds__(256)
void gemm_nt_kernel(const float* __restrict__ A, const float* __restrict__ W,
                    float* __restrict__ C, int M, int N, int K)
{
    __shared__ float As[32][68];   // 68 = float4-aligned pad, odd bank stride
    __shared__ float Bs[32][68];

    const int tid = threadIdx.x;
    const int tx = tid & 15;       // 0..15 -> n
    const int ty = tid >> 4;       // 0..15 -> m
    const int m0 = blockIdx.y * 64;
    const int n0 = blockIdx.x * 64;

    float acc[4][4] = {};

    for (int k0 = 0; k0 < K; k0 += 32) {
        // Cooperative load: 64 rows x 32 k for both tiles (2 float4 per thread each)
        #pragma unroll
        for (int i = 0; i < 2; ++i) {
            const int idx = tid + i * 256;      // 0..511
            const int row = idx >> 3;           // 0..63
            const int k4  = (idx & 7) << 2;     // 0,4,..,28
            const float4 va = *(const float4*)(A + (size_t)(m0 + row) * K + k0 + k4);
            As[k4 + 0][row] = va.x; As[k4 + 1][row] = va.y;
            As[k4 + 2][row] = va.z; As[k4 + 3][row] = va.w;
            const float4 vb = *(const float4*)(W + (size_t)(n0 + row) * K + k0 + k4);
            Bs[k4 + 0][row] = vb.x; Bs[k4 + 1][row] = vb.y;
            Bs[k4 + 2][row] = vb.z; Bs[k4 + 3][row] = vb.w;
        }
        __syncthreads();

        #pragma unroll
        for (int kk = 0; kk < 32; ++kk) {
            const float4 a4 = *(const float4*)&As[kk][ty * 4];
            const float4 b4 = *(const float4*)&Bs[kk][tx * 4];
            const float av[4] = {a4.x, a4.y, a4.z, a4.w};
            const float bv[4] = {b4.x, b4.y, b4.z, b4.w};
            #pragma unroll
            for (int i = 0; i < 4; ++i)
                #pragma unroll
                for (int j = 0; j < 4; ++j)
                    acc[i][j] = fmaf(av[i], bv[j], acc[i][j]);
        }
        __syncthreads();
    }

    #pragma unroll
    for (int i = 0; i < 4; ++i) {
        const float4 o = make_float4(acc[i][0], acc[i][1], acc[i][2], acc[i][3]);
        *(float4*)(C + (size_t)(m0 + ty * 4 + i) * N + n0 + tx * 4) = o;
    }
}

// ---------------------------------------------------------------------------
// Flash attention with ALiBi (causal). One wave (64 threads) per block; each
// lane owns one q-row: q (64 regs) and O-accumulator (64 regs) live entirely
// in registers. K/V rows are read at wave-uniform addresses (scalarizable to
// s_load by the compiler). Online softmax over k-tiles of 32; future k-tiles
// skipped entirely (causal).
// qkv layout: [B*L][3*E]; Q at col h*D, K at E + h*D, V at 2*E + h*D.
// ---------------------------------------------------------------------------
__global__ __launch_bounds__(64)
void attn_kernel(const float* __restrict__ qkv, float* __restrict__ ctx)
{
    const int qt   = blockIdx.x;            // 0..31, q-tile of 64 rows
    const int bh   = blockIdx.y;            // 0..31
    const int b    = bh >> 4;
    const int h    = bh & 15;
    const int lane = threadIdx.x;           // 0..63
    const int qrow = qt * 64 + lane;        // q position in [0, L)

    const float* qp = qkv + ((size_t)(b * LL + qrow)) * (3 * EE) + h * DD;
    float4 q[16];
    #pragma unroll
    for (int i = 0; i < 16; ++i) q[i] = *(const float4*)(qp + 4 * i);

    const float slope = exp2f(-0.5f * (float)(h + 1));  // 2^(-8/H*(h+1)), H=16
    const float scale = 0.125f;                         // 1/sqrt(D)

    float o[64];
    #pragma unroll
    for (int i = 0; i < 64; ++i) o[i] = 0.f;
    float m = -1e30f, l = 0.f;

    const float* Kb = qkv + ((size_t)b * LL) * (3 * EE) + EE + h * DD;
    const float* Vb = Kb + EE;

    const int ktiles = qt * 2 + 2;          // covers k in [0, qt*64+64)
    for (int kt = 0; kt < ktiles; ++kt) {
        const int kbase = kt * 32;

        // S = q . K^T for 32 keys (K rows wave-uniform -> scalar loads)
        float s[32];
        #pragma unroll
        for (int j = 0; j < 32; ++j) {
            const float* kr = Kb + (size_t)(kbase + j) * (3 * EE);
            float acc = 0.f;
            #pragma unroll
            for (int i = 0; i < 16; ++i) {
                const float4 kv = *(const float4*)(kr + 4 * i);
                acc = fmaf(q[i].x, kv.x, acc);
                acc = fmaf(q[i].y, kv.y, acc);
                acc = fmaf(q[i].z, kv.z, acc);
                acc = fmaf(q[i].w, kv.w, acc);
            }
            s[j] = acc;
        }

        // scale + ALiBi bias + causal mask; tile max
        float mt = m;
        #pragma unroll
        for (int j = 0; j < 32; ++j) {
            const int k = kbase + j;
            s[j] = (k <= qrow) ? fmaf(slope, (float)(k - qrow), s[j] * scale)
                               : -1e30f;
            mt = fmaxf(mt, s[j]);
        }

        // online-softmax rescale
        const float r = __expf(m - mt);     // first tile: exp(-huge) = 0, no NaN
        l *= r;
        #pragma unroll
        for (int i = 0; i < 64; ++i) o[i] *= r;
        m = mt;

        // P·V accumulate (V rows wave-uniform -> scalar loads)
        #pragma unroll
        for (int j = 0; j < 32; ++j) {
            const float p = __expf(s[j] - mt);   // masked -> exp(-huge) = 0
            l += p;
            const float* vr = Vb + (size_t)(kbase + j) * (3 * EE);
            #pragma unroll
            for (int i = 0; i < 16; ++i) {
                const float4 vv = *(const float4*)(vr + 4 * i);
                o[4 * i + 0] = fmaf(p, vv.x, o[4 * i + 0]);
                o[4 * i + 1] = fmaf(p, vv.y, o[4 * i + 1]);
                o[4 * i + 2] = fmaf(p, vv.z, o[4 * i + 2]);
                o[4 * i + 3] = fmaf(p, vv.w, o[4 * i + 3]);
            }
        }
    }

    const float inv = 1.f / l;
    float* cp = ctx + ((size_t)(b * LL + qrow)) * EE + h * DD;
    #pragma unroll
    for (int i = 0; i < 16; ++i) {
        const float4 ov = make_float4(o[4 * i + 0] * inv, o[4 * i + 1] * inv,
                                      o[4 * i + 2] * inv, o[4 * i + 3] * inv);
        *(float4*)(cp + 4 * i) = ov;
    }
}

// ---------------------------------------------------------------------------
// Launch: x @ w_in^T -> qkv (ws) ; flash-attn -> ctx (ws) ; ctx @ w_out^T -> out
// ws usage: qkv 48 MB + ctx 16 MB = 64 MB, fully overwritten every call.
// ---------------------------------------------------------------------------
extern "C" void kernel_launch(void* const* d_in, const int* in_sizes, int n_in,
                              void* d_out, int out_size, void* d_ws, size_t ws_size,
                              hipStream_t stream)
{
    const float* x     = (const float*)d_in[0];   // (B, L, E)
    const float* w_in  = (const float*)d_in[1];   // (3E, E)
    const float* w_out = (const float*)d_in[2];   // (E, E)
    float* out = (float*)d_out;                   // (B, L, E)

    float* qkv = (float*)d_ws;                       // [4096][3072]
    float* ctx = qkv + (size_t)4096 * 3072;          // [4096][1024]

    // QKV projection: (4096 x 3072) = (4096 x 1024) * (3072 x 1024)^T
    gemm_nt_kernel<<<dim3(3072 / 64, 4096 / 64), 256, 0, stream>>>(
        x, w_in, qkv, 4096, 3072, 1024);

    // Attention: grid (q-tiles, B*H)
    attn_kernel<<<dim3(LL / 64, BB * HH), 64, 0, stream>>>(qkv, ctx);

    // Output projection: (4096 x 1024) = (4096 x 1024) * (1024 x 1024)^T
    gemm_nt_kernel<<<dim3(1024 / 64, 4096 / 64), 256, 0, stream>>>(
        ctx, w_out, out, 4096, 1024, 1024);
}

// Round 8
// 1238.114 us; speedup vs baseline: 2.8488x; 2.8488x over previous
//
#include <hip/hip_runtime.h>
#include <math.h>

// Problem constants (reference: B=2, L=2048, E=1024, H=16, D=64)
#define BB 2
#define LL 2048
#define EE 1024
#define HH 16
#define DD 64

// ---------------------------------------------------------------------------
// GEMM (NT): C[M][N] = A[M][K] * W[N][K]^T
// A row-major [M][K], W row-major [N][K]. Tile 128x128, BK=32, 256 threads,
// 8x8 micro-tile per thread. LDS tiles stored k-major ([kk][row], pad 132)
// so the inner loop reads contiguous float4 fragments (ds_read_b128).
// ---------------------------------------------------------------------------
__global__ __launch_bounds__(256)
void gemm_nt_kernel(const float* __restrict__ A, const float* __restrict__ W,
                    float* __restrict__ C, int M, int N, int K)
{
    __shared__ float As[32][132];   // k-major, pad 132 (float4-aligned, odd/32 stride)
    __shared__ float Bs[32][132];

    const int tid = threadIdx.x;
    const int tx = tid & 15;        // 0..15 -> n
    const int ty = tid >> 4;        // 0..15 -> m
    const int m0 = blockIdx.y * 128;
    const int n0 = blockIdx.x * 128;

    float acc[8][8] = {};

    for (int k0 = 0; k0 < K; k0 += 32) {
        // Cooperative load: 128 rows x 32 k for both tiles (4 float4/thread each)
        #pragma unroll
        for (int i = 0; i < 4; ++i) {
            const int idx = tid + i * 256;      // 0..1023
            const int row = idx >> 3;           // 0..127
            const int k4  = (idx & 7) << 2;     // 0,4,..,28
            const float4 va = *(const float4*)(A + (size_t)(m0 + row) * K + k0 + k4);
            As[k4 + 0][row] = va.x; As[k4 + 1][row] = va.y;
            As[k4 + 2][row] = va.z; As[k4 + 3][row] = va.w;
            const float4 vb = *(const float4*)(W + (size_t)(n0 + row) * K + k0 + k4);
            Bs[k4 + 0][row] = vb.x; Bs[k4 + 1][row] = vb.y;
            Bs[k4 + 2][row] = vb.z; Bs[k4 + 3][row] = vb.w;
        }
        __syncthreads();

        #pragma unroll
        for (int kk = 0; kk < 32; ++kk) {
            const float4 a0 = *(const float4*)&As[kk][ty * 8];
            const float4 a1 = *(const float4*)&As[kk][ty * 8 + 4];
            const float4 b0 = *(const float4*)&Bs[kk][tx * 8];
            const float4 b1 = *(const float4*)&Bs[kk][tx * 8 + 4];
            const float av[8] = {a0.x, a0.y, a0.z, a0.w, a1.x, a1.y, a1.z, a1.w};
            const float bv[8] = {b0.x, b0.y, b0.z, b0.w, b1.x, b1.y, b1.z, b1.w};
            #pragma unroll
            for (int i = 0; i < 8; ++i)
                #pragma unroll
                for (int j = 0; j < 8; ++j)
                    acc[i][j] = fmaf(av[i], bv[j], acc[i][j]);
        }
        __syncthreads();
    }

    #pragma unroll
    for (int i = 0; i < 8; ++i) {
        float* cp = C + (size_t)(m0 + ty * 8 + i) * N + n0 + tx * 8;
        *(float4*)(cp + 0) = make_float4(acc[i][0], acc[i][1], acc[i][2], acc[i][3]);
        *(float4*)(cp + 4) = make_float4(acc[i][4], acc[i][5], acc[i][6], acc[i][7]);
    }
}

// ---------------------------------------------------------------------------
// Flash attention with ALiBi (causal), GEMM-shaped. 256 threads (4 waves),
// QBLK = KBLK = 64. Per k-tile: S = Q.K^T as a 64x64x64 GEMM (Q,K staged
// k-major in LDS), online softmax (16-lane shfl row reductions), P written
// k-major to LDS, then O += P.V as a second 64x64x64 GEMM.
// Thread (ty,tx) owns S/O rows ty*4..+3, cols tx*4..+3.
// qkv layout: [B*L][3*E]; Q at col h*D, K at E + h*D, V at 2*E + h*D.
// ---------------------------------------------------------------------------
__global__ __launch_bounds__(256)
void attn_kernel(const float* __restrict__ qkv, float* __restrict__ ctx)
{
    __shared__ float Qs[64][68];   // k-major: Qs[d][qr], pre-scaled by 1/sqrt(D)
    __shared__ float Ks[64][68];   // k-major: Ks[d][kr]
    __shared__ float Vs[64][68];   // row-major: Vs[kr][d]
    __shared__ float Ps[64][68];   // k-major: Ps[kr][qr]

    const int qt  = blockIdx.x;    // 0..31 q-tile
    const int bh  = blockIdx.y;    // 0..31
    const int b   = bh >> 4;
    const int h   = bh & 15;
    const int tid = threadIdx.x;
    const int tx  = tid & 15;
    const int ty  = tid >> 4;
    const int q0  = qt * 64;

    const float slope = exp2f(-0.5f * (float)(h + 1));  // 2^(-8/H*(h+1)), H=16
    const float scale = 0.125f;                         // 1/sqrt(64)

    // Stage Q (transposed + pre-scaled)
    const float* Qb = qkv + ((size_t)(b * LL + q0)) * (3 * EE) + h * DD;
    #pragma unroll
    for (int i = 0; i < 4; ++i) {
        const int idx = tid + i * 256;      // 0..1023 = 64 rows x 16 float4
        const int qr  = idx >> 4;           // 0..63
        const int d4  = (idx & 15) << 2;    // 0,4,..,60
        const float4 v = *(const float4*)(Qb + (size_t)qr * (3 * EE) + d4);
        Qs[d4 + 0][qr] = v.x * scale; Qs[d4 + 1][qr] = v.y * scale;
        Qs[d4 + 2][qr] = v.z * scale; Qs[d4 + 3][qr] = v.w * scale;
    }

    const float* Kb = qkv + ((size_t)(b * LL)) * (3 * EE) + EE + h * DD;
    const float* Vb = Kb + EE;

    float o[4][4] = {};
    float mrun[4], lrun[4];
    #pragma unroll
    for (int i = 0; i < 4; ++i) { mrun[i] = -1e30f; lrun[i] = 0.f; }

    for (int kt = 0; kt <= qt; ++kt) {
        const int kb = kt * 64;

        __syncthreads();   // previous PV (and Q staging) done before overwrite
        #pragma unroll
        for (int i = 0; i < 4; ++i) {
            const int idx = tid + i * 256;
            const int kr  = idx >> 4;
            const int d4  = (idx & 15) << 2;
            const float4 kv = *(const float4*)(Kb + (size_t)(kb + kr) * (3 * EE) + d4);
            Ks[d4 + 0][kr] = kv.x; Ks[d4 + 1][kr] = kv.y;
            Ks[d4 + 2][kr] = kv.z; Ks[d4 + 3][kr] = kv.w;
            const float4 vv = *(const float4*)(Vb + (size_t)(kb + kr) * (3 * EE) + d4);
            *(float4*)&Vs[kr][d4] = vv;
        }
        __syncthreads();

        // S = Q.K^T (pre-scaled)
        float s[4][4] = {};
        #pragma unroll
        for (int d = 0; d < 64; ++d) {
            const float4 a4 = *(const float4*)&Qs[d][ty * 4];
            const float4 b4 = *(const float4*)&Ks[d][tx * 4];
            const float av[4] = {a4.x, a4.y, a4.z, a4.w};
            const float bv[4] = {b4.x, b4.y, b4.z, b4.w};
            #pragma unroll
            for (int i = 0; i < 4; ++i)
                #pragma unroll
                for (int j = 0; j < 4; ++j)
                    s[i][j] = fmaf(av[i], bv[j], s[i][j]);
        }

        // ALiBi bias + causal mask (mask only bites on the diagonal tile)
        #pragma unroll
        for (int i = 0; i < 4; ++i) {
            const int q = q0 + ty * 4 + i;
            #pragma unroll
            for (int j = 0; j < 4; ++j) {
                const int k = kb + tx * 4 + j;
                s[i][j] += slope * (float)(k - q);
                if (k > q) s[i][j] = -1e30f;
            }
        }

        // Online softmax: row reductions across the 16 tx lanes (same ty)
        #pragma unroll
        for (int i = 0; i < 4; ++i) {
            float tm = fmaxf(fmaxf(s[i][0], s[i][1]), fmaxf(s[i][2], s[i][3]));
            tm = fmaxf(tm, __shfl_xor(tm, 1));
            tm = fmaxf(tm, __shfl_xor(tm, 2));
            tm = fmaxf(tm, __shfl_xor(tm, 4));
            tm = fmaxf(tm, __shfl_xor(tm, 8));
            const float mnew = fmaxf(mrun[i], tm);
            const float r = __expf(mrun[i] - mnew);   // first tile: exp(-huge)=0
            mrun[i] = mnew;
            float rs = 0.f;
            #pragma unroll
            for (int j = 0; j < 4; ++j) {
                s[i][j] = __expf(s[i][j] - mnew);     // masked -> 0
                rs += s[i][j];
            }
            rs += __shfl_xor(rs, 1);
            rs += __shfl_xor(rs, 2);
            rs += __shfl_xor(rs, 4);
            rs += __shfl_xor(rs, 8);
            lrun[i] = lrun[i] * r + rs;
            #pragma unroll
            for (int j = 0; j < 4; ++j) o[i][j] *= r;
        }

        // P -> LDS, k-major: Ps[kr][qr]
        #pragma unroll
        for (int j = 0; j < 4; ++j)
            *(float4*)&Ps[tx * 4 + j][ty * 4] =
                make_float4(s[0][j], s[1][j], s[2][j], s[3][j]);
        __syncthreads();

        // O += P.V
        #pragma unroll
        for (int kr = 0; kr < 64; ++kr) {
            const float4 p4 = *(const float4*)&Ps[kr][ty * 4];  // broadcast over tx
            const float4 v4 = *(const float4*)&Vs[kr][tx * 4];
            const float pv[4] = {p4.x, p4.y, p4.z, p4.w};
            const float vv[4] = {v4.x, v4.y, v4.z, v4.w};
            #pragma unroll
            for (int i = 0; i < 4; ++i)
                #pragma unroll
                for (int j = 0; j < 4; ++j)
                    o[i][j] = fmaf(pv[i], vv[j], o[i][j]);
        }
    }

    // Epilogue: normalize and store
    #pragma unroll
    for (int i = 0; i < 4; ++i) {
        const float inv = 1.f / lrun[i];
        float* cp = ctx + ((size_t)(b * LL + q0 + ty * 4 + i)) * EE + h * DD + tx * 4;
        *(float4*)cp = make_float4(o[i][0] * inv, o[i][1] * inv,
                                   o[i][2] * inv, o[i][3] * inv);
    }
}

// ---------------------------------------------------------------------------
// Launch: x @ w_in^T -> qkv (ws) ; flash-attn -> ctx (ws) ; ctx @ w_out^T -> out
// ws usage: qkv 48 MB + ctx 16 MB = 64 MB, fully overwritten every call.
// ---------------------------------------------------------------------------
extern "C" void kernel_launch(void* const* d_in, const int* in_sizes, int n_in,
                              void* d_out, int out_size, void* d_ws, size_t ws_size,
                              hipStream_t stream)
{
    const float* x     = (const float*)d_in[0];   // (B, L, E)
    const float* w_in  = (const float*)d_in[1];   // (3E, E)
    const float* w_out = (const float*)d_in[2];   // (E, E)
    float* out = (float*)d_out;                   // (B, L, E)

    float* qkv = (float*)d_ws;                    // [4096][3072]
    float* ctx = qkv + (size_t)4096 * 3072;       // [4096][1024]

    // QKV projection: (4096 x 3072) = (4096 x 1024) * (3072 x 1024)^T
    gemm_nt_kernel<<<dim3(3072 / 128, 4096 / 128), 256, 0, stream>>>(
        x, w_in, qkv, 4096, 3072, 1024);

    // Attention: grid (q-tiles, B*H)
    attn_kernel<<<dim3(LL / 64, BB * HH), 256, 0, stream>>>(qkv, ctx);

    // Output projection: (4096 x 1024) = (4096 x 1024) * (1024 x 1024)^T
    gemm_nt_kernel<<<dim3(1024 / 128, 4096 / 128), 256, 0, stream>>>(
        ctx, w_out, out, 4096, 1024, 1024);
}

// Round 15
// 1032.613 us; speedup vs baseline: 3.4158x; 1.1990x over previous
//
#include <hip/hip_runtime.h>
#include <math.h>

// Problem constants (reference: B=2, L=2048, E=1024, H=16, D=64)
#define BB 2
#define LL 2048
#define EE 1024
#define HH 16
#define DD 64

// ---------------------------------------------------------------------------
// GEMM (NT): C[M][N] = A[M][K] * W[N][K]^T
// A row-major [M][K], W row-major [N][K]. Tile 128x128, BK=32, 256 threads,
// 8x8 micro-tile per thread. LDS tiles stored k-major ([kk][row], pad 132)
// so the inner loop reads contiguous float4 fragments (ds_read_b128).
// (unchanged this round: ~400 us combined, ~86 TF; attn is the target)
// ---------------------------------------------------------------------------
__global__ __launch_bounds__(256)
void gemm_nt_kernel(const float* __restrict__ A, const float* __restrict__ W,
                    float* __restrict__ C, int M, int N, int K)
{
    __shared__ float As[32][132];   // k-major, pad 132 (float4-aligned, odd/32 stride)
    __shared__ float Bs[32][132];

    const int tid = threadIdx.x;
    const int tx = tid & 15;        // 0..15 -> n
    const int ty = tid >> 4;        // 0..15 -> m
    const int m0 = blockIdx.y * 128;
    const int n0 = blockIdx.x * 128;

    float acc[8][8] = {};

    for (int k0 = 0; k0 < K; k0 += 32) {
        // Cooperative load: 128 rows x 32 k for both tiles (4 float4/thread each)
        #pragma unroll
        for (int i = 0; i < 4; ++i) {
            const int idx = tid + i * 256;      // 0..1023
            const int row = idx >> 3;           // 0..127
            const int k4  = (idx & 7) << 2;     // 0,4,..,28
            const float4 va = *(const float4*)(A + (size_t)(m0 + row) * K + k0 + k4);
            As[k4 + 0][row] = va.x; As[k4 + 1][row] = va.y;
            As[k4 + 2][row] = va.z; As[k4 + 3][row] = va.w;
            const float4 vb = *(const float4*)(W + (size_t)(n0 + row) * K + k0 + k4);
            Bs[k4 + 0][row] = vb.x; Bs[k4 + 1][row] = vb.y;
            Bs[k4 + 2][row] = vb.z; Bs[k4 + 3][row] = vb.w;
        }
        __syncthreads();

        #pragma unroll
        for (int kk = 0; kk < 32; ++kk) {
            const float4 a0 = *(const float4*)&As[kk][ty * 8];
            const float4 a1 = *(const float4*)&As[kk][ty * 8 + 4];
            const float4 b0 = *(const float4*)&Bs[kk][tx * 8];
            const float4 b1 = *(const float4*)&Bs[kk][tx * 8 + 4];
            const float av[8] = {a0.x, a0.y, a0.z, a0.w, a1.x, a1.y, a1.z, a1.w};
            const float bv[8] = {b0.x, b0.y, b0.z, b0.w, b1.x, b1.y, b1.z, b1.w};
            #pragma unroll
            for (int i = 0; i < 8; ++i)
                #pragma unroll
                for (int j = 0; j < 8; ++j)
                    acc[i][j] = fmaf(av[i], bv[j], acc[i][j]);
        }
        __syncthreads();
    }

    #pragma unroll
    for (int i = 0; i < 8; ++i) {
        float* cp = C + (size_t)(m0 + ty * 8 + i) * N + n0 + tx * 8;
        *(float4*)(cp + 0) = make_float4(acc[i][0], acc[i][1], acc[i][2], acc[i][3]);
        *(float4*)(cp + 4) = make_float4(acc[i][4], acc[i][5], acc[i][6], acc[i][7]);
    }
}

// ---------------------------------------------------------------------------
// Flash attention with ALiBi (causal), GEMM-shaped. 256 threads (4 waves),
// QBLK = KBLK = 64.
// R8 changes (occupancy was 6.4%, LDS-capped at 2 blocks/CU + inverted LPT):
//  - P buffer ALIASES Ks (K dead after S-GEMM; one extra barrier) ->
//    LDS 69.6 KB -> 52.2 KB -> 3 blocks/CU (12 waves/CU).
//  - qt = gridDim.x-1-blockIdx.x: heavy causal blocks dispatch first (LPT),
//    light blocks pack the scheduling tail.
// ---------------------------------------------------------------------------
__global__ __launch_bounds__(256)
void attn_kernel(const float* __restrict__ qkv, float* __restrict__ ctx)
{
    __shared__ float Qs[64][68];   // k-major: Qs[d][qr], pre-scaled by 1/sqrt(D)
    __shared__ float Ks[64][68];   // k-major: Ks[d][kr]; REUSED as Ps[kr][qr]
    __shared__ float Vs[64][68];   // row-major: Vs[kr][d]

    const int qt  = gridDim.x - 1 - blockIdx.x;  // LPT: heavy blocks first
    const int bh  = blockIdx.y;    // 0..31
    const int b   = bh >> 4;
    const int h   = bh & 15;
    const int tid = threadIdx.x;
    const int tx  = tid & 15;
    const int ty  = tid >> 4;
    const int q0  = qt * 64;

    const float slope = exp2f(-0.5f * (float)(h + 1));  // 2^(-8/H*(h+1)), H=16
    const float scale = 0.125f;                         // 1/sqrt(64)

    // Stage Q (transposed + pre-scaled)
    const float* Qb = qkv + ((size_t)(b * LL + q0)) * (3 * EE) + h * DD;
    #pragma unroll
    for (int i = 0; i < 4; ++i) {
        const int idx = tid + i * 256;      // 0..1023 = 64 rows x 16 float4
        const int qr  = idx >> 4;           // 0..63
        const int d4  = (idx & 15) << 2;    // 0,4,..,60
        const float4 v = *(const float4*)(Qb + (size_t)qr * (3 * EE) + d4);
        Qs[d4 + 0][qr] = v.x * scale; Qs[d4 + 1][qr] = v.y * scale;
        Qs[d4 + 2][qr] = v.z * scale; Qs[d4 + 3][qr] = v.w * scale;
    }

    const float* Kb = qkv + ((size_t)(b * LL)) * (3 * EE) + EE + h * DD;
    const float* Vb = Kb + EE;

    float o[4][4] = {};
    float mrun[4], lrun[4];
    #pragma unroll
    for (int i = 0; i < 4; ++i) { mrun[i] = -1e30f; lrun[i] = 0.f; }

    for (int kt = 0; kt <= qt; ++kt) {
        const int kb = kt * 64;

        __syncthreads();   // prev PV reads (Ks-as-P, Vs) + Q staging done
        #pragma unroll
        for (int i = 0; i < 4; ++i) {
            const int idx = tid + i * 256;
            const int kr  = idx >> 4;
            const int d4  = (idx & 15) << 2;
            const float4 kv = *(const float4*)(Kb + (size_t)(kb + kr) * (3 * EE) + d4);
            Ks[d4 + 0][kr] = kv.x; Ks[d4 + 1][kr] = kv.y;
            Ks[d4 + 2][kr] = kv.z; Ks[d4 + 3][kr] = kv.w;
            const float4 vv = *(const float4*)(Vb + (size_t)(kb + kr) * (3 * EE) + d4);
            *(float4*)&Vs[kr][d4] = vv;
        }
        __syncthreads();

        // S = Q.K^T (pre-scaled)
        float s[4][4] = {};
        #pragma unroll
        for (int d = 0; d < 64; ++d) {
            const float4 a4 = *(const float4*)&Qs[d][ty * 4];
            const float4 b4 = *(const float4*)&Ks[d][tx * 4];
            const float av[4] = {a4.x, a4.y, a4.z, a4.w};
            const float bv[4] = {b4.x, b4.y, b4.z, b4.w};
            #pragma unroll
            for (int i = 0; i < 4; ++i)
                #pragma unroll
                for (int j = 0; j < 4; ++j)
                    s[i][j] = fmaf(av[i], bv[j], s[i][j]);
        }

        // ALiBi bias + causal mask (mask only bites on the diagonal tile)
        #pragma unroll
        for (int i = 0; i < 4; ++i) {
            const int q = q0 + ty * 4 + i;
            #pragma unroll
            for (int j = 0; j < 4; ++j) {
                const int k = kb + tx * 4 + j;
                s[i][j] += slope * (float)(k - q);
                if (k > q) s[i][j] = -1e30f;
            }
        }

        // Online softmax: row reductions across the 16 tx lanes (same ty)
        #pragma unroll
        for (int i = 0; i < 4; ++i) {
            float tm = fmaxf(fmaxf(s[i][0], s[i][1]), fmaxf(s[i][2], s[i][3]));
            tm = fmaxf(tm, __shfl_xor(tm, 1));
            tm = fmaxf(tm, __shfl_xor(tm, 2));
            tm = fmaxf(tm, __shfl_xor(tm, 4));
            tm = fmaxf(tm, __shfl_xor(tm, 8));
            const float mnew = fmaxf(mrun[i], tm);
            const float r = __expf(mrun[i] - mnew);   // first tile: exp(-huge)=0
            mrun[i] = mnew;
            float rs = 0.f;
            #pragma unroll
            for (int j = 0; j < 4; ++j) {
                s[i][j] = __expf(s[i][j] - mnew);     // masked -> 0
                rs += s[i][j];
            }
            rs += __shfl_xor(rs, 1);
            rs += __shfl_xor(rs, 2);
            rs += __shfl_xor(rs, 4);
            rs += __shfl_xor(rs, 8);
            lrun[i] = lrun[i] * r + rs;
            #pragma unroll
            for (int j = 0; j < 4; ++j) o[i][j] *= r;
        }

        __syncthreads();   // all S-GEMM reads of Ks done before P overwrites it

        // P -> LDS, k-major, ALIASED into Ks: Ks[kr][qr]
        #pragma unroll
        for (int j = 0; j < 4; ++j)
            *(float4*)&Ks[tx * 4 + j][ty * 4] =
                make_float4(s[0][j], s[1][j], s[2][j], s[3][j]);
        __syncthreads();

        // O += P.V  (P read from Ks alias)
        #pragma unroll
        for (int kr = 0; kr < 64; ++kr) {
            const float4 p4 = *(const float4*)&Ks[kr][ty * 4];  // broadcast over tx
            const float4 v4 = *(const float4*)&Vs[kr][tx * 4];
            const float pv[4] = {p4.x, p4.y, p4.z, p4.w};
            const float vv[4] = {v4.x, v4.y, v4.z, v4.w};
            #pragma unroll
            for (int i = 0; i < 4; ++i)
                #pragma unroll
                for (int j = 0; j < 4; ++j)
                    o[i][j] = fmaf(pv[i], vv[j], o[i][j]);
        }
    }

    // Epilogue: normalize and store
    #pragma unroll
    for (int i = 0; i < 4; ++i) {
        const float inv = 1.f / lrun[i];
        float* cp = ctx + ((size_t)(b * LL + q0 + ty * 4 + i)) * EE + h * DD + tx * 4;
        *(float4*)cp = make_float4(o[i][0] * inv, o[i][1] * inv,
                                   o[i][2] * inv, o[i][3] * inv);
    }
}

// ---------------------------------------------------------------------------
// Launch: x @ w_in^T -> qkv (ws) ; flash-attn -> ctx (ws) ; ctx @ w_out^T -> out
// ws usage: qkv 48 MB + ctx 16 MB = 64 MB, fully overwritten every call.
// ---------------------------------------------------------------------------
extern "C" void kernel_launch(void* const* d_in, const int* in_sizes, int n_in,
                              void* d_out, int out_size, void* d_ws, size_t ws_size,
                              hipStream_t stream)
{
    const float* x     = (const float*)d_in[0];   // (B, L, E)
    const float* w_in  = (const float*)d_in[1];   // (3E, E)
    const float* w_out = (const float*)d_in[2];   // (E, E)
    float* out = (float*)d_out;                   // (B, L, E)

    float* qkv = (float*)d_ws;                    // [4096][3072]
    float* ctx = qkv + (size_t)4096 * 3072;       // [4096][1024]

    // QKV projection: (4096 x 3072) = (4096 x 1024) * (3072 x 1024)^T
    gemm_nt_kernel<<<dim3(3072 / 128, 4096 / 128), 256, 0, stream>>>(
        x, w_in, qkv, 4096, 3072, 1024);

    // Attention: grid (q-tiles, B*H)
    attn_kernel<<<dim3(LL / 64, BB * HH), 256, 0, stream>>>(qkv, ctx);

    // Output projection: (4096 x 1024) = (4096 x 1024) * (1024 x 1024)^T
    gemm_nt_kernel<<<dim3(1024 / 128, 4096 / 128), 256, 0, stream>>>(
        ctx, w_out, out, 4096, 1024, 1024);
}